// Round 1
// baseline (176.829 us; speedup 1.0000x reference)
//
#include <hip/hip_runtime.h>
#include <math.h>

// LorentzConv1d: B=32, C=16, L=16384, k=9, pad=4, stride=1, OUT_CH=64, K_VAL=1
// concat dim = 1 + 15*9 = 136; W is (63, 136); out (32, 64, 16384) fp32.
// d-index layout: d = 1 + j*15 + (c-1) for tap j in [0,9), space channel c in [1,16).
// x channel 0 is NEVER used (time is recomputed per patch from the window).

namespace {
constexpr int TP = 256;      // positions per block
constexpr int KS = 9;
constexpr int PADL = 4;
constexpr int CIN = 16;
constexpr int CSP = 15;      // space channels
constexpr int LEN = 16384;
constexpr int NB = 32;
constexpr int OUTC = 64;
constexpr int NW = 63;       // real W rows
constexpr int CD = 136;
constexpr int TILE_W = TP + 2 * PADL;  // 264
}

__global__ __launch_bounds__(256, 4)
void lorentz_conv1d(const float* __restrict__ x, const float* __restrict__ W,
                    const float* __restrict__ bias, float* __restrict__ out) {
  __shared__ float xt[CSP * TILE_W];   // 15 x 264 floats = 15840 B
  __shared__ float4 red[4][64];        // 4 KB cross-wave h^2 reduction

  const int tid = threadIdx.x;
  const int b = blockIdx.y;
  const int p0 = blockIdx.x * TP;

  // ---- stage space channels (1..15) for positions [p0-4, p0+260) , zero-padded
  for (int idx = tid; idx < CSP * TILE_W; idx += 256) {
    const int c = idx / TILE_W;            // 0..14 -> channel c+1
    const int q = idx - c * TILE_W;
    const int g = p0 - PADL + q;
    float v = 0.0f;
    if (g >= 0 && g < LEN) v = x[(b * CIN + (c + 1)) * LEN + g];
    xt[idx] = v;
  }
  __syncthreads();

  const int wv = __builtin_amdgcn_readfirstlane(tid >> 6);  // wave id, SGPR
  const int lane = tid & 63;
  const int obase = wv * 16;           // this wave's W-row block

  // lane owns 4 consecutive positions: P = p0 + 4*lane + p, p in [0,4)
  float acc[16][4];
#pragma unroll
  for (int oo = 0; oo < 16; ++oo)
#pragma unroll
    for (int p = 0; p < 4; ++p) acc[oo][p] = 0.0f;

  float csq[12];  // per-position-column sum over channels of x^2 (12-wide window)
#pragma unroll
  for (int i = 0; i < 12; ++i) csq[i] = 0.0f;

  const float4* xt4 = reinterpret_cast<const float4*>(xt);

  for (int c = 1; c <= CSP; ++c) {
    // lane's 12-float window of channel c: tile dwords [4*lane, 4*lane+12)
    const int rb = (c - 1) * (TILE_W / 4) + lane;
    const float4 xa = xt4[rb];
    const float4 xb = xt4[rb + 1];
    const float4 xc = xt4[rb + 2];
    float xr[12] = {xa.x, xa.y, xa.z, xa.w, xb.x, xb.y, xb.z, xb.w,
                    xc.x, xc.y, xc.z, xc.w};

#pragma unroll
    for (int i = 0; i < 12; ++i) csq[i] = fmaf(xr[i], xr[i], csq[i]);

#pragma unroll
    for (int oo = 0; oo < 16; ++oo) {
      const int o = obase + oo;
      if (o < NW) {                      // uniform scalar branch; row 63 virtual
        const float* wrow = W + o * CD + c;  // d = j*15 + c
#pragma unroll
        for (int j = 0; j < KS; ++j) {
          const float w = wrow[j * CSP];     // wave-uniform -> s_load
#pragma unroll
          for (int p = 0; p < 4; ++p)
            acc[oo][p] = fmaf(w, xr[p + j], acc[oo][p]);
        }
      }
    }
  }

  // ---- patch time = sqrt(1 + window sum of squares)
  float tme[4];
#pragma unroll
  for (int p = 0; p < 4; ++p) {
    float s = 0.0f;
#pragma unroll
    for (int j = 0; j < KS; ++j) s += csq[p + j];
    tme[p] = sqrtf(1.0f + s);
  }

  // ---- time-channel term + bias + relu + partial h^2
  float psum[4] = {0.0f, 0.0f, 0.0f, 0.0f};
#pragma unroll
  for (int oo = 0; oo < 16; ++oo) {
    const int o = obase + oo;
    if (o < NW) {
      const float w0 = W[o * CD];
      const float bo = bias[o];
#pragma unroll
      for (int p = 0; p < 4; ++p) {
        float h = fmaf(w0, tme[p], acc[oo][p]) + bo;
        h = fmaxf(h, 0.0f);
        acc[oo][p] = h;
        psum[p] = fmaf(h, h, psum[p]);
      }
    }
  }

  // ---- coalesced float4 stores of h channels (out channel = o+1)
  float4* out4 = reinterpret_cast<float4*>(out);
  const int pos4 = (p0 >> 2) + lane;
#pragma unroll
  for (int oo = 0; oo < 16; ++oo) {
    const int o = obase + oo;
    if (o < NW) {
      float4 v = make_float4(acc[oo][0], acc[oo][1], acc[oo][2], acc[oo][3]);
      out4[(b * OUTC + (o + 1)) * (LEN / 4) + pos4] = v;
    }
  }

  // ---- cross-wave reduce h^2 -> t_out (channel 0)
  red[wv][lane] = make_float4(psum[0], psum[1], psum[2], psum[3]);
  __syncthreads();
  if (wv == 0) {
    const float4 r0 = red[0][lane], r1 = red[1][lane];
    const float4 r2 = red[2][lane], r3 = red[3][lane];
    float4 t;
    t.x = sqrtf(1.0f + r0.x + r1.x + r2.x + r3.x);
    t.y = sqrtf(1.0f + r0.y + r1.y + r2.y + r3.y);
    t.z = sqrtf(1.0f + r0.z + r1.z + r2.z + r3.z);
    t.w = sqrtf(1.0f + r0.w + r1.w + r2.w + r3.w);
    out4[(b * OUTC + 0) * (LEN / 4) + pos4] = t;
  }
}

extern "C" void kernel_launch(void* const* d_in, const int* in_sizes, int n_in,
                              void* d_out, int out_size, void* d_ws, size_t ws_size,
                              hipStream_t stream) {
  const float* x = (const float*)d_in[0];
  const float* W = (const float*)d_in[1];
  const float* bias = (const float*)d_in[2];
  float* out = (float*)d_out;
  dim3 grid(LEN / TP, NB);
  hipLaunchKernelGGL(lorentz_conv1d, grid, dim3(256), 0, stream, x, W, bias, out);
}

// Round 3
// 61.930 us; speedup vs baseline: 2.8553x; 2.8553x over previous
//
#include <hip/hip_runtime.h>
#include <math.h>

typedef __bf16 bf16x8 __attribute__((ext_vector_type(8)));
typedef float f32x4 __attribute__((ext_vector_type(4)));
typedef unsigned short u16t;

namespace {
constexpr int B_ = 32, CIN = 16, CSP = 15, L_ = 16384;
constexpr int KS = 9, PAD = 4, OUTC = 64, NW = 63, CD = 136;
constexpr int PP = 256;            // positions per block
constexpr int KT = 160;            // padded K: 10 taps * 16 channel slots
constexpr int NKS = 5;             // K-steps of 32
constexpr int XROWS = PP + 16;     // 272 staged window rows

constexpr int OFF_XT = 0;                         // [272][16] bf16 = 8704 B
constexpr int OFF_CSQ = OFF_XT + XROWS * 16 * 2;  // [272] f32
constexpr int OFF_TM = OFF_CSQ + XROWS * 4;       // [256] f32
constexpr int LDS_BYTES = OFF_TM + PP * 4;        // 10816 B

__device__ inline u16t f2bf(float v) {
  unsigned ui = __float_as_uint(v);
  return (u16t)((ui + 0x7fffu + ((ui >> 16) & 1u)) >> 16);
}
__device__ inline float bf2f(u16t u) { return __uint_as_float(((unsigned)u) << 16); }
}

// Prepack W (63x136 fp32) -> wbf[64][160] bf16, k = jt*16 + cs; pads zeroed.
__global__ void prep_w(const float* __restrict__ W, u16t* __restrict__ wbf) {
  int i = blockIdx.x * 256 + threadIdx.x;
  if (i >= OUTC * KT) return;
  int o = i / KT, kk = i - o * KT;
  int jt = kk >> 4, cs = kk & 15;
  float v = 0.f;
  if (o < NW && jt < KS && cs < CSP) v = W[o * CD + 1 + jt * CSP + cs];
  wbf[i] = f2bf(v);
}

__global__ __launch_bounds__(256, 3)
void lorentz_mfma(const float* __restrict__ x, const float* __restrict__ W,
                  const float* __restrict__ bias, const u16t* __restrict__ wbf,
                  float* __restrict__ out) {
  __shared__ __align__(16) char lds[LDS_BYTES];
  const int tid = threadIdx.x;
  const int b = blockIdx.y;
  const int p0 = blockIdx.x * PP;

  // ---- P1: stage x (channels 1..15) position-major: Xt[row t][ch cs] bf16
  u16t* Xt = (u16t*)(lds + OFF_XT);
  for (int t = tid; t < XROWS; t += 256) Xt[t * 16 + 15] = 0;  // dummy ch, NaN-safe
  for (int e = tid; e < CSP * XROWS; e += 256) {
    int cs = e / XROWS;
    int t = e - cs * XROWS;
    int g = p0 - PAD + t;
    float v = 0.f;
    if (g >= 0 && g < L_) v = x[((size_t)b * CIN + cs + 1) * L_ + g];
    Xt[t * 16 + cs] = f2bf(v);
  }
  __syncthreads();

  // ---- P2: per-window-column sum of squares (ch15 is zero, include freely)
  {
    float* csq = (float*)(lds + OFF_CSQ);
    for (int t = tid; t < XROWS; t += 256) {
      const uint4* row = (const uint4*)(Xt + t * 16);
      uint4 a = row[0], c = row[1];
      unsigned wds[8] = {a.x, a.y, a.z, a.w, c.x, c.y, c.z, c.w};
      float s = 0.f;
#pragma unroll
      for (int i = 0; i < 8; ++i) {
        float lo = bf2f((u16t)(wds[i] & 0xffffu));
        float hi = bf2f((u16t)(wds[i] >> 16));
        s = fmaf(lo, lo, s);
        s = fmaf(hi, hi, s);
      }
      csq[t] = s;
    }
  }
  __syncthreads();

  // ---- P3: MFMA
  const int wv = tid >> 6;
  const int lane = tid & 63;
  const int q = lane >> 4, r = lane & 15;
  const int jtq = q >> 1, half = q & 1;

  uint4 wfrag[4][NKS];  // B operand: row 16*rb + r, k-slice [32ks+8q, +8)
#pragma unroll
  for (int rb = 0; rb < 4; ++rb)
#pragma unroll
    for (int ks = 0; ks < NKS; ++ks)
      wfrag[rb][ks] = *(const uint4*)(wbf + (16 * rb + r) * KT + ks * 32 + q * 8);

  float w0v[4], bv[4];
#pragma unroll
  for (int rb = 0; rb < 4; ++rb) {
    int row = 16 * rb + r;
    w0v[rb] = (row < NW) ? W[row * CD] : 0.f;
    bv[rb] = (row < NW) ? bias[row] : 0.f;
  }

#pragma unroll
  for (int si = 0; si < 4; ++si) {
    const int s = wv + 4 * si;  // 16-position subtile

    // time channel for this subtile (same-wave LDS write->read, in-order)
    if (lane < 16) {
      const float* csq = (const float*)(lds + OFF_CSQ);
      int pos = s * 16 + lane;
      float ss = 0.f;
#pragma unroll
      for (int j = 0; j < KS; ++j) ss += csq[pos + j];
      ((float*)(lds + OFF_TM))[pos] = sqrtf(1.f + ss);
    }

    // A fragments: lane (q,r) holds patch[pos = s*16+r][k = 32ks+8q .. +7]
    // = Xt[row = s*16 + r + 2ks + (q>>1)][8*(q&1) .. +7] — one b128 each.
    bf16x8 av[NKS];
#pragma unroll
    for (int ks = 0; ks < NKS; ++ks) {
      int row = s * 16 + r + 2 * ks + jtq;
      av[ks] = *(const bf16x8*)(lds + OFF_XT + row * 32 + half * 16);
    }

    f32x4 acc[4];
#pragma unroll
    for (int rb = 0; rb < 4; ++rb) acc[rb] = (f32x4){0.f, 0.f, 0.f, 0.f};
#pragma unroll
    for (int ks = 0; ks < NKS; ++ks) {
#pragma unroll
      for (int rb = 0; rb < 4; ++rb) {
        union { uint4 u; bf16x8 v; } w;
        w.u = wfrag[rb][ks];
        acc[rb] = __builtin_amdgcn_mfma_f32_16x16x32_bf16(av[ks], w.v, acc[rb], 0, 0, 0);
      }
    }

    // epilogue: h = relu(acc + w0*time + bias); float4 stores; t_out shfl-reduce
    const float4 tmv = *(const float4*)(lds + OFF_TM + (s * 16 + q * 4) * 4);
    const float tm[4] = {tmv.x, tmv.y, tmv.z, tmv.w};
    float psum[4] = {0.f, 0.f, 0.f, 0.f};
#pragma unroll
    for (int rb = 0; rb < 4; ++rb) {
      int row = 16 * rb + r;
      float h[4];
#pragma unroll
      for (int g = 0; g < 4; ++g) {
        float hh = fmaf(w0v[rb], tm[g], acc[rb][g]) + bv[rb];
        hh = fmaxf(hh, 0.f);
        h[g] = hh;
        psum[g] = fmaf(hh, hh, psum[g]);
      }
      if (row < NW) {
        *(float4*)(out + ((size_t)b * OUTC + row + 1) * L_ + p0 + s * 16 + q * 4) =
            make_float4(h[0], h[1], h[2], h[3]);
      }
    }
#pragma unroll
    for (int m = 1; m <= 8; m <<= 1) {
#pragma unroll
      for (int g = 0; g < 4; ++g) psum[g] += __shfl_xor(psum[g], m, 64);
    }
    if (r == 0) {
      float4 t = make_float4(sqrtf(1.f + psum[0]), sqrtf(1.f + psum[1]),
                             sqrtf(1.f + psum[2]), sqrtf(1.f + psum[3]));
      *(float4*)(out + ((size_t)b * OUTC) * L_ + p0 + s * 16 + q * 4) = t;
    }
  }
}

extern "C" void kernel_launch(void* const* d_in, const int* in_sizes, int n_in,
                              void* d_out, int out_size, void* d_ws, size_t ws_size,
                              hipStream_t stream) {
  const float* x = (const float*)d_in[0];
  const float* W = (const float*)d_in[1];
  const float* bias = (const float*)d_in[2];
  float* out = (float*)d_out;
  u16t* wbf = (u16t*)d_ws;  // 64*160*2 = 20480 B

  hipLaunchKernelGGL(prep_w, dim3((OUTC * KT + 255) / 256), dim3(256), 0, stream, W, wbf);
  hipLaunchKernelGGL(lorentz_mfma, dim3(L_ / PP, B_), dim3(256), 0, stream,
                     x, W, bias, wbf, out);
}